// Round 1
// baseline (237.574 us; speedup 1.0000x reference)
//
#include <hip/hip_runtime.h>

// Problem constants
#define NB      32      // batch
#define INF     128     // in_flt
#define NPIX    64      // N
#define TSP     16      // t
#define OUTF    32      // out_flt
#define FF      16      // intermediate features
#define D_IN    768     // 3*t*t
#define D_OUT   8192    // out_flt*t*t
#define NCOL    (D_OUT*FF)   // 131072
#define OUTCH   160     // in_flt + out_flt
#define BSTRIDE 655360  // 160*64*64 floats per batch in d_out
#define MOFF    524288  // 128*64*64: offset of out_a region per batch (M scratch)

// K1: fused strided conv (128ch,4x4,stride4 -> 3ch) + x->out concat copy.
// Block = (b, oi): reads x[b, :, 4oi..4oi+3, :] once, writes the same to out,
// produces x_r[b, :, oi, :] accumulated into At[k][b] (transposed A for K2).
__global__ __launch_bounds__(256) void k1_conv_copy(
    const float* __restrict__ x, const float* __restrict__ wc,
    float* __restrict__ out, float* __restrict__ At)
{
    __shared__ float sW[3*128*16];     // w_conv, 6144 floats = 24 KB
    __shared__ float sP[16][16][3];    // partials [icg][j][c3]
    const int b   = blockIdx.x >> 4;
    const int oi  = blockIdx.x & 15;
    const int tid = threadIdx.x;
    for (int idx = tid; idx < 6144; idx += 256) sW[idx] = wc[idx];
    __syncthreads();
    const int icg = tid >> 4;          // 0..15 -> ic block of 8
    const int j   = tid & 15;          // output col
    float a0 = 0.f, a1 = 0.f, a2 = 0.f;
    for (int ic8 = 0; ic8 < 8; ++ic8) {
        const int ic = icg*8 + ic8;
        #pragma unroll
        for (int ki = 0; ki < 4; ++ki) {
            const int row = 4*oi + ki;
            const float4 xv = *(const float4*)(x + ((size_t)(b*INF+ic)*NPIX + row)*NPIX + 4*j);
            *(float4*)(out + ((size_t)(b*OUTCH+ic)*NPIX + row)*NPIX + 4*j) = xv;
            const float* w0 = sW + ((0*INF+ic)*4 + ki)*4;
            const float* w1 = sW + ((1*INF+ic)*4 + ki)*4;
            const float* w2 = sW + ((2*INF+ic)*4 + ki)*4;
            a0 += xv.x*w0[0] + xv.y*w0[1] + xv.z*w0[2] + xv.w*w0[3];
            a1 += xv.x*w1[0] + xv.y*w1[1] + xv.z*w1[2] + xv.w*w1[3];
            a2 += xv.x*w2[0] + xv.y*w2[1] + xv.z*w2[2] + xv.w*w2[3];
        }
    }
    sP[icg][j][0] = a0; sP[icg][j][1] = a1; sP[icg][j][2] = a2;
    __syncthreads();
    if (tid < 48) {
        const int c3 = tid >> 4, jj = tid & 15;
        float s = 0.f;
        #pragma unroll
        for (int g = 0; g < 16; ++g) s += sP[g][jj][c3];
        const int k = c3*256 + oi*16 + jj;    // reshape(3,16,16) C-order
        At[k*32 + b] = s;
    }
}

// K2: M[b, col] = sum_k At[k][b] * T[k, col].  col = d*16+f in [0,131072).
// A staged in LDS (96 KB, broadcast ds_read_b128); each thread = 1 column,
// 32 fp32 accumulators. M written into the out_a slots of d_out (scratch).
__global__ __launch_bounds__(512) void k2_gemm(
    const float* __restrict__ At, const float* __restrict__ Tm,
    float* __restrict__ out)
{
    extern __shared__ float sA[];      // D_IN*32 = 24576 floats = 96 KB
    const int tid = threadIdx.x;
    for (int idx = tid; idx < D_IN*32; idx += 512) sA[idx] = At[idx];
    __syncthreads();
    const int col = blockIdx.x*512 + tid;
    float acc[32];
    #pragma unroll
    for (int b = 0; b < 32; ++b) acc[b] = 0.f;
    const float* tp = Tm + col;
    #pragma unroll 8
    for (int k = 0; k < D_IN; ++k) {
        const float tv = tp[(size_t)k * NCOL];
        const float4* ap = (const float4*)(sA + k*32);
        #pragma unroll
        for (int b4 = 0; b4 < 8; ++b4) {
            const float4 a = ap[b4];
            acc[b4*4+0] += a.x*tv;
            acc[b4*4+1] += a.y*tv;
            acc[b4*4+2] += a.z*tv;
            acc[b4*4+3] += a.w*tv;
        }
    }
    #pragma unroll
    for (int b = 0; b < 32; ++b)
        out[(size_t)b*BSTRIDE + MOFF + col] = acc[b];
}

// K3: out[j,d] = sum_i exp(-sum_f |M[i,d,f]-M[j,d,f]|) - 1.
// Block = 32 d's; M tile in LDS padded 16->17 to break bank conflicts.
__global__ __launch_bounds__(256) void k3_pairs(
    const float* __restrict__ outM,    // d_out base (M lives in out_a slots)
    float* __restrict__ outS)
{
    extern __shared__ float sM[];      // 32*32*17 floats = 69632 B
    const int tid = threadIdx.x;
    const int dd0 = blockIdx.x * 32;
    for (int idx = tid; idx < 32*32*16; idx += 256) {
        const int i = idx >> 9, rem = idx & 511, d = rem >> 4, f = rem & 15;
        sM[(i*32 + d)*17 + f] =
            outM[(size_t)i*BSTRIDE + MOFF + (size_t)(dd0 + d)*16 + f];
    }
    __syncthreads();
    const int j = tid >> 3;
    for (int q = 0; q < 4; ++q) {
        const int d = (tid & 7) + q*8;
        float mj[16];
        const float* pj = sM + (j*32 + d)*17;
        #pragma unroll
        for (int f = 0; f < 16; ++f) mj[f] = pj[f];
        float acc = 0.f;
        for (int i = 0; i < 32; ++i) {
            const float* pi = sM + (i*32 + d)*17;
            float dist = 0.f;
            #pragma unroll
            for (int f = 0; f < 16; ++f) dist += fabsf(pi[f] - mj[f]);
            acc += __expf(-dist);
        }
        outS[(size_t)j*D_OUT + dd0 + d] = acc - 1.0f;
    }
}

// K4: ConvTranspose2d, stride==kernel -> no overlap:
// out_a[b,oc,4si+ki,4sj+kj] = sum_ic outS[b,ic,si,sj] * wd[ic,oc,ki,kj].
// Overwrites the M scratch region with the real output.
__global__ __launch_bounds__(256) void k4_deconv(
    const float* __restrict__ outS, const float* __restrict__ wd,
    float* __restrict__ out)
{
    __shared__ float sO[32*256];       // [ic][si*16+sj], 32 KB
    __shared__ float sWd[32*16];       // [ic][ki*4+kj]
    const int b   = blockIdx.x >> 5;
    const int oc  = blockIdx.x & 31;
    const int tid = threadIdx.x;
    for (int idx = tid; idx < 8192; idx += 256) sO[idx] = outS[(size_t)b*D_OUT + idx];
    for (int idx = tid; idx < 512; idx += 256) {
        const int ic = idx >> 4, r = idx & 15;
        sWd[idx] = wd[((ic*32 + oc) << 4) + r];   // IOHW: (ic, oc, ki, kj)
    }
    __syncthreads();
    float* ob = out + (size_t)b*BSTRIDE + (size_t)(128 + oc)*4096;
    for (int s = 0; s < 16; ++s) {
        const int p  = tid + (s << 8);
        const int i  = p >> 6, jc = p & 63;
        const int si = i >> 2, ki = i & 3, sj = jc >> 2, kj = jc & 3;
        float acc = 0.f;
        #pragma unroll
        for (int ic = 0; ic < 32; ++ic)
            acc += sO[ic*256 + si*16 + sj] * sWd[ic*16 + ki*4 + kj];
        ob[p] = acc;
    }
}

extern "C" void kernel_launch(void* const* d_in, const int* in_sizes, int n_in,
                              void* d_out, int out_size, void* d_ws, size_t ws_size,
                              hipStream_t stream) {
    const float* x  = (const float*)d_in[0];
    const float* wc = (const float*)d_in[1];
    const float* Tm = (const float*)d_in[2];
    const float* wd = (const float*)d_in[3];
    float* out  = (float*)d_out;
    float* At   = (float*)d_ws;                        // 98304 B
    float* outS = (float*)((char*)d_ws + (1 << 17));   // 1 MB at +128 KB

    k1_conv_copy<<<NB*TSP, 256, 0, stream>>>(x, wc, out, At);       // 512 blocks
    k2_gemm    <<<NCOL/512, 512, D_IN*32*sizeof(float), stream>>>(At, Tm, out); // 256 blocks
    k3_pairs   <<<D_OUT/32, 256, 32*32*17*sizeof(float), stream>>>(out, outS);  // 256 blocks
    k4_deconv  <<<NB*OUTF, 256, 0, stream>>>(outS, wd, out);        // 1024 blocks
}

// Round 2
// 230.219 us; speedup vs baseline: 1.0319x; 1.0319x over previous
//
#include <hip/hip_runtime.h>

// Problem constants
#define NB      32      // batch
#define INF     128     // in_flt
#define NPIX    64      // N
#define TSP     16      // t
#define OUTF    32      // out_flt
#define FF      16      // intermediate features
#define D_IN    768     // 3*t*t
#define D_OUT   8192    // out_flt*t*t
#define NCOL    (D_OUT*FF)   // 131072
#define OUTCH   160     // in_flt + out_flt
#define BSTRIDE 655360  // 160*64*64 floats per batch in d_out
#define MOFF    524288  // 128*64*64: offset of out_a region per batch (M scratch)

// K1: fused strided conv (128ch,4x4,stride4 -> 3ch) + x->out concat copy.
__global__ __launch_bounds__(256) void k1_conv_copy(
    const float* __restrict__ x, const float* __restrict__ wc,
    float* __restrict__ out, float* __restrict__ At)
{
    __shared__ float sW[3*128*16];     // w_conv, 24 KB
    __shared__ float sP[16][16][3];    // partials [icg][j][c3]
    const int b   = blockIdx.x >> 4;
    const int oi  = blockIdx.x & 15;
    const int tid = threadIdx.x;
    for (int idx = tid; idx < 6144; idx += 256) sW[idx] = wc[idx];
    __syncthreads();
    const int icg = tid >> 4;          // 0..15 -> ic block of 8
    const int j   = tid & 15;          // output col
    float a0 = 0.f, a1 = 0.f, a2 = 0.f;
    for (int ic8 = 0; ic8 < 8; ++ic8) {
        const int ic = icg*8 + ic8;
        #pragma unroll
        for (int ki = 0; ki < 4; ++ki) {
            const int row = 4*oi + ki;
            const float4 xv = *(const float4*)(x + ((size_t)(b*INF+ic)*NPIX + row)*NPIX + 4*j);
            *(float4*)(out + ((size_t)(b*OUTCH+ic)*NPIX + row)*NPIX + 4*j) = xv;
            const float* w0 = sW + ((0*INF+ic)*4 + ki)*4;
            const float* w1 = sW + ((1*INF+ic)*4 + ki)*4;
            const float* w2 = sW + ((2*INF+ic)*4 + ki)*4;
            a0 += xv.x*w0[0] + xv.y*w0[1] + xv.z*w0[2] + xv.w*w0[3];
            a1 += xv.x*w1[0] + xv.y*w1[1] + xv.z*w1[2] + xv.w*w1[3];
            a2 += xv.x*w2[0] + xv.y*w2[1] + xv.z*w2[2] + xv.w*w2[3];
        }
    }
    sP[icg][j][0] = a0; sP[icg][j][1] = a1; sP[icg][j][2] = a2;
    __syncthreads();
    if (tid < 48) {
        const int c3 = tid >> 4, jj = tid & 15;
        float s = 0.f;
        #pragma unroll
        for (int g = 0; g < 16; ++g) s += sP[g][jj][c3];
        const int k = c3*256 + oi*16 + jj;    // reshape(3,16,16) C-order
        At[k*32 + b] = s;
    }
}

// K2: M[b, col] = sum_k At[k][b] * T[k, col].
// A-reads are wave-UNIFORM -> compiler lowers to s_load (SMEM/K$ path);
// no LDS in the inner loop (R0 was LDS-issue-bound: 8 waves x 768 x 8
// ds_read_b128 per CU ~= 245 us of LDS pipe). Per k: 1 coalesced T load
// + 8 scalar float4 A loads + 32 v_fmac.
__global__ __launch_bounds__(512) void k2_gemm(
    const float* __restrict__ At, const float* __restrict__ Tm,
    float* __restrict__ out)
{
    const int col = blockIdx.x*512 + threadIdx.x;
    float acc[32];
    #pragma unroll
    for (int b = 0; b < 32; ++b) acc[b] = 0.f;
    const float* tp = Tm + col;
    #pragma unroll 8
    for (int k = 0; k < D_IN; ++k) {
        const float tv = tp[(size_t)k * NCOL];
        #pragma unroll
        for (int b4 = 0; b4 < 8; ++b4) {
            const float4 a = *(const float4*)(At + k*32 + b4*4);  // uniform addr
            acc[b4*4+0] += a.x*tv;
            acc[b4*4+1] += a.y*tv;
            acc[b4*4+2] += a.z*tv;
            acc[b4*4+3] += a.w*tv;
        }
    }
    #pragma unroll
    for (int b = 0; b < 32; ++b)
        out[(size_t)b*BSTRIDE + MOFF + col] = acc[b];
}

// K3: out[j,d] = sum_i exp(-sum_f |M[i,d,f]-M[j,d,f]|) - 1.
__global__ __launch_bounds__(256) void k3_pairs(
    const float* __restrict__ outM,    // d_out base (M lives in out_a slots)
    float* __restrict__ outS)
{
    extern __shared__ float sM[];      // 32*32*17 floats
    const int tid = threadIdx.x;
    const int dd0 = blockIdx.x * 32;
    for (int idx = tid; idx < 32*32*16; idx += 256) {
        const int i = idx >> 9, rem = idx & 511, d = rem >> 4, f = rem & 15;
        sM[(i*32 + d)*17 + f] =
            outM[(size_t)i*BSTRIDE + MOFF + (size_t)(dd0 + d)*16 + f];
    }
    __syncthreads();
    const int j = tid >> 3;
    for (int q = 0; q < 4; ++q) {
        const int d = (tid & 7) + q*8;
        float mj[16];
        const float* pj = sM + (j*32 + d)*17;
        #pragma unroll
        for (int f = 0; f < 16; ++f) mj[f] = pj[f];
        float acc = 0.f;
        for (int i = 0; i < 32; ++i) {
            const float* pi = sM + (i*32 + d)*17;
            float dist = 0.f;
            #pragma unroll
            for (int f = 0; f < 16; ++f) dist += fabsf(pi[f] - mj[f]);
            acc += __expf(-dist);
        }
        outS[(size_t)j*D_OUT + dd0 + d] = acc - 1.0f;
    }
}

// K4: ConvTranspose2d, stride==kernel -> no overlap.
__global__ __launch_bounds__(256) void k4_deconv(
    const float* __restrict__ outS, const float* __restrict__ wd,
    float* __restrict__ out)
{
    __shared__ float sO[32*256];       // [ic][si*16+sj]
    __shared__ float sWd[32*16];       // [ic][ki*4+kj]
    const int b   = blockIdx.x >> 5;
    const int oc  = blockIdx.x & 31;
    const int tid = threadIdx.x;
    for (int idx = tid; idx < 8192; idx += 256) sO[idx] = outS[(size_t)b*D_OUT + idx];
    for (int idx = tid; idx < 512; idx += 256) {
        const int ic = idx >> 4, r = idx & 15;
        sWd[idx] = wd[((ic*32 + oc) << 4) + r];   // IOHW: (ic, oc, ki, kj)
    }
    __syncthreads();
    float* ob = out + (size_t)b*BSTRIDE + (size_t)(128 + oc)*4096;
    for (int s = 0; s < 16; ++s) {
        const int p  = tid + (s << 8);
        const int i  = p >> 6, jc = p & 63;
        const int si = i >> 2, ki = i & 3, sj = jc >> 2, kj = jc & 3;
        float acc = 0.f;
        #pragma unroll
        for (int ic = 0; ic < 32; ++ic)
            acc += sO[ic*256 + si*16 + sj] * sWd[ic*16 + ki*4 + kj];
        ob[p] = acc;
    }
}

extern "C" void kernel_launch(void* const* d_in, const int* in_sizes, int n_in,
                              void* d_out, int out_size, void* d_ws, size_t ws_size,
                              hipStream_t stream) {
    const float* x  = (const float*)d_in[0];
    const float* wc = (const float*)d_in[1];
    const float* Tm = (const float*)d_in[2];
    const float* wd = (const float*)d_in[3];
    float* out  = (float*)d_out;
    float* At   = (float*)d_ws;                        // 98304 B
    float* outS = (float*)((char*)d_ws + (1 << 17));   // 1 MB at +128 KB

    k1_conv_copy<<<NB*TSP, 256, 0, stream>>>(x, wc, out, At);       // 512 blocks
    k2_gemm    <<<NCOL/512, 512, 0, stream>>>(At, Tm, out);         // 256 blocks
    k3_pairs   <<<D_OUT/32, 256, 32*32*17*sizeof(float), stream>>>(out, outS);  // 256 blocks
    k4_deconv  <<<NB*OUTF, 256, 0, stream>>>(outS, wd, out);        // 1024 blocks
}